// Round 6
// baseline (1414.943 us; speedup 1.0000x reference)
//
#include <hip/hip_runtime.h>
#include <math.h>
#include <stdint.h>

#define N1 4096
#define N2 65536
#define DIM 1024
#define KNN 4
#define CSPLIT 32
#define BM 128
#define BN 128
#define COLS_PER_SPLIT (N2 / CSPLIT)          // 2048
#define TILES_PER_SPLIT (COLS_PER_SPLIT / BN) // 16
#define NCAND 32
#define SCSTR 68    // Sc stride (floats): 16B-aligned rows, bank-spread scans

typedef __attribute__((ext_vector_type(8))) int int32x8;
typedef __attribute__((ext_vector_type(4))) float f32x4;

#define GLDS16(g, l)                                                          \
    __builtin_amdgcn_global_load_lds(                                         \
        (const __attribute__((address_space(1))) void*)(g),                   \
        (__attribute__((address_space(3))) void*)(l), 16, 0, 0)

// ---- fp32 -> fp8 e4m3fn (OCP), RNE, saturate to 448, subnormal-correct ----
__device__ __forceinline__ unsigned int f2fp8(float x) {
    const unsigned int u = __float_as_uint(x);
    const unsigned int s = (u >> 24) & 0x80u;
    const float ax = fminf(__uint_as_float(u & 0x7fffffffu), 448.f);
    int e = (int)(__float_as_uint(ax) >> 23) - 127;
    e = e < -6 ? -6 : e;
    const float q = rintf(ldexpf(ax, 3 - e));   // normals: [8,16]; subnorm: [0,8]
    return s | (unsigned int)((e + 6) * 8 + (int)q);  // q=16 carries into exponent
}

// ---------------- fp32 -> fp8 convert ----------------
// Row = 1024 fp8 bytes = 64 16B-units = 32 32B-chunks. Within each 128B K-slice
// (4 chunks), chunk c stores source chunk c ^ (row&3): 32B-chunk XOR swizzle so a
// GEMM fragment (32B) is ONE contiguous int32x8 load (2x ds_read_b128 into
// consecutive VGPRs, zero pack movs) after forced-linear global_load_lds staging.
// Unit-level: unit u stores source u ^ ((row&3)<<1).
// Synth path (invn != nullptr): rows encoded as x*(16/|row|) -> GEMM scores are
// cosine*16 (uniform scale, ranking unchanged; x16 keeps normalized elements out
// of the fp8 subnormal range). invn keeps TRUE 1/|row| for the exact rescore.
__global__ void convert_fp8_kernel(const float* __restrict__ src,
                                   uint8_t* __restrict__ dst,
                                   float* __restrict__ invn) {
    const int t = threadIdx.x;
    const int row = blockIdx.x * 32 + (t >> 3);
    const int u = t & 7;
    const int sw = (row & 3) << 1;             // 32B-chunk granularity
    const float* srow = src + ((size_t)row << 10);
    uint8_t* drow = dst + ((size_t)row << 10);
    float scale = 1.0f;
    if (invn != nullptr) {
        float ss = 0.f;
#pragma unroll
        for (int k = 0; k < 8; ++k) {
            const float* p = srow + ((k * 8 + (u ^ sw)) << 4);
#pragma unroll
            for (int g = 0; g < 4; ++g) {
                const float4 v = *(const float4*)(p + g * 4);
                ss += v.x * v.x + v.y * v.y + v.z * v.z + v.w * v.w;
            }
        }
#pragma unroll
        for (int off = 1; off < 8; off <<= 1) ss += __shfl_xor(ss, off, 64);
        const float inv = 1.0f / sqrtf(ss);
        scale = 16.0f * inv;
        if (u == 0) invn[row] = inv;
    }
#pragma unroll
    for (int k = 0; k < 8; ++k) {
        const float* p = srow + ((k * 8 + (u ^ sw)) << 4);
        unsigned int wv[4];
#pragma unroll
        for (int g = 0; g < 4; ++g) {
            const float4 v = *(const float4*)(p + g * 4);
            wv[g] = f2fp8(v.x * scale) | (f2fp8(v.y * scale) << 8) |
                    (f2fp8(v.z * scale) << 16) | (f2fp8(v.w * scale) << 24);
        }
        *(uint4*)(drow + ((k * 8 + u) << 4)) = make_uint4(wv[0], wv[1], wv[2], wv[3]);
    }
}

// ---------------- fp8 MFMA GEMM (K=128 scaled, scale==1.0) + running top-4 ----------------
// Block: 128 rows x 2048 cols (16 tiles of 128), K=1024, BK=128 -> 8 stages.
// 4 waves 2x2; wave = 64x64 via 4x4 grid of mfma_scale_f32_16x16x128_f8f6f4.
// R1 pipeline: 2x32KB LDS dbuf, counted vmcnt(8) (vmcnt(0) only at st=7).
// Stage body: barrier(A) -> 16x int32x8 frag loads -> 16x MFMA, with the issue
// order pinned by sched_group_barrier (DS_READ x16 then MFMA x16) -- NO explicit
// lgkmcnt(0) drain: the compiler's waitcnt pass emits partial lgkmcnt(N) so the
// read-burst tail overlaps the first MFMAs. Live ranges == R1 (no spills).
__global__ __launch_bounds__(256, 2) void gemm_topk_fp8(
    const uint8_t* __restrict__ qbf, const uint8_t* __restrict__ sbf,
    float* __restrict__ pScore, int* __restrict__ pIdx) {
    __shared__ __align__(16) char smem[65536];   // [2][As 16K | Bs 16K]; Sc aliases
    float* const Sc = (float*)smem;

    const int tid = threadIdx.x;
    const int l = tid & 63;
    const int w = tid >> 6;
    const int waveM = w >> 1;
    const int waveN = w & 1;
    const int rowBase = blockIdx.y * BM;
    const int colSplit = blockIdx.x;
    const int colStart = colSplit * COLS_PER_SPLIT;

    // staging: wave w, instr i covers rows i*32 + w*8 + (l>>3), unit l&7
    const uint8_t* aSrc =
        qbf + ((size_t)(rowBase + w * 8 + (l >> 3)) << 10) + (l & 7) * 16;
    const uint8_t* bSrc0 =
        sbf + ((size_t)(colStart + w * 8 + (l >> 3)) << 10) + (l & 7) * 16;

    // fragment read: m = l&15, K-chunk q4 = l>>4; source 32B chunk q4 stored at
    // chunk q4 ^ (row&3); row&3 == am&3. One contiguous int32x8 per fragment.
    const int am = l & 15;
    const int q4 = l >> 4;
    const int p = q4 ^ (am & 3);
    const int aOff = (waveM * 64 + am) * 128 + p * 32;   // + i*2048
    const int bOff = (waveN * 64 + am) * 128 + p * 32;   // + j*2048

    const unsigned int one_scales = 0x7f7f7f7fu;  // E8M0 127 -> x1.0 any byte

    const int scanRow = tid >> 1;
    const int sub = tid & 1;
    float tv0 = -1e30f, tv1 = -1e30f, tv2 = -1e30f, tv3 = -1e30f;
    int ti0 = colStart, ti1 = colStart, ti2 = colStart, ti3 = colStart;
    float thr = -1e30f;                           // == min(tv0..tv3), cached

    auto insert4 = [&](float val, int idx) {
        float mn = tv0; int mi = 0;
        if (tv1 < mn) { mn = tv1; mi = 1; }
        if (tv2 < mn) { mn = tv2; mi = 2; }
        if (tv3 < mn) { mn = tv3; mi = 3; }
        if (mi == 0)      { tv0 = val; ti0 = idx; }
        else if (mi == 1) { tv1 = val; ti1 = idx; }
        else if (mi == 2) { tv2 = val; ti2 = idx; }
        else              { tv3 = val; ti3 = idx; }
        thr = fminf(fminf(tv0, tv1), fminf(tv2, tv3));
    };
    auto scanCmp = [&](const f32x4 v, int ibase) {
        const float m4 = fmaxf(fmaxf(v[0], v[1]), fmaxf(v[2], v[3]));
        if (m4 > thr) {
#pragma unroll
            for (int e = 0; e < 4; ++e)
                if (v[e] > thr) insert4(v[e], ibase + e);
        }
    };

    for (int tile = 0; tile < TILES_PER_SPLIT; ++tile) {
        const int colBase = colStart + tile * BN;
        const uint8_t* bSrc = bSrc0 + ((size_t)tile << 17);  // +tile*128*1024

        auto stage_st = [&](int st) {    // 8 global_load_lds per wave per stage
            char* const dst = smem + (st & 1) * 32768 + w * 1024;
            const int kB = st * 128;
#pragma unroll
            for (int i = 0; i < 4; ++i) {
                GLDS16(aSrc + (size_t)i * 32768 + kB, dst + i * 4096);
                GLDS16(bSrc + (size_t)i * 32768 + kB, dst + 16384 + i * 4096);
            }
        };
        __syncthreads();                 // prev tile's Sc scan reads done
        stage_st(0);                     // 16 DMA in flight
        stage_st(1);

        f32x4 acc[4][4];
#pragma unroll
        for (int i = 0; i < 4; ++i)
#pragma unroll
            for (int j = 0; j < 4; ++j) acc[i][j] = (f32x4)0.f;

#pragma unroll
        for (int st = 0; st < 8; ++st) {
            // stage st's 8 loads done; stage st+1's 8 (newest) stay in flight
            if (st < 7) asm volatile("s_waitcnt vmcnt(8)" ::: "memory");
            else        asm volatile("s_waitcnt vmcnt(0)" ::: "memory");
            __builtin_amdgcn_s_barrier();            // (A) st data visible to all
            __builtin_amdgcn_sched_barrier(0);       // no hoisting above (A)
            const char* const curA = smem + (st & 1) * 32768;
            const char* const curB = curA + 16384;
            int32x8 af[4], bf[4];
#pragma unroll
            for (int i = 0; i < 4; ++i)
                af[i] = *(const int32x8*)(curA + aOff + i * 2048);
#pragma unroll
            for (int j = 0; j < 4; ++j)
                bf[j] = *(const int32x8*)(curB + bOff + j * 2048);
            __builtin_amdgcn_s_setprio(1);
#pragma unroll
            for (int i = 0; i < 4; ++i)
#pragma unroll
                for (int j = 0; j < 4; ++j)
                    acc[i][j] = __builtin_amdgcn_mfma_scale_f32_16x16x128_f8f6f4(
                        af[i], bf[j], acc[i][j], 0, 0,   // cbsz=0 (e4m3), blgp=0
                        0, one_scales, 0, one_scales);
            __builtin_amdgcn_s_setprio(0);
            // pin issue order: all 16 ds_reads, then 16 MFMAs (live ranges == R1);
            // waitcnt pass inserts PARTIAL lgkmcnt(N) per consuming MFMA.
            __builtin_amdgcn_sched_group_barrier(0x100, 16, 0);  // DS_READ x16
            __builtin_amdgcn_sched_group_barrier(0x008, 16, 0);  // MFMA x16
            // all reads consumed by MFMAs => LDS->VGPR complete before last MFMA;
            // barrier(B) then makes buffer overwrite safe.
            __builtin_amdgcn_s_barrier();            // (B)
            __builtin_amdgcn_sched_barrier(0);       // DMA stays below (B)
            if (st < 6) stage_st(st + 2);            // overwrite safe; in flight
        }

        // epilogue: scores through Sc (aliases staging - fully drained at st=7)
#pragma unroll
        for (int h = 0; h < 2; ++h) {
            if (waveN == h) {
#pragma unroll
                for (int i = 0; i < 4; ++i)
#pragma unroll
                    for (int j = 0; j < 4; ++j) {
                        const int scCol = j * 16 + am;
#pragma unroll
                        for (int r = 0; r < 4; ++r)
                            Sc[(waveM * 64 + i * 16 + q4 * 4 + r) * SCSTR + scCol] =
                                acc[i][j][r];
                    }
            }
            __syncthreads();
            {
                const float* srow = Sc + scanRow * SCSTR + sub * 32;
                const int base = colBase + h * 64 + sub * 32;
#pragma unroll
                for (int c4 = 0; c4 < 8; ++c4) {
                    const f32x4 v = *(const f32x4*)(srow + c4 * 4);
                    scanCmp(v, base + c4 * 4);
                }
            }
            if (h == 0) __syncthreads();  // scan reads done before h=1 Sc writes
        }
    }

    const int prow = rowBase + scanRow;
    const size_t pbase = (((size_t)prow * CSPLIT + colSplit) * 2 + sub) * 4;
    pScore[pbase + 0] = tv0; pIdx[pbase + 0] = ti0;
    pScore[pbase + 1] = tv1; pIdx[pbase + 1] = ti1;
    pScore[pbase + 2] = tv2; pIdx[pbase + 2] = ti2;
    pScore[pbase + 3] = tv3; pIdx[pbase + 3] = ti3;
}

// ------- merge 256 partials -> approx top-32 -> exact fp32 rescore -> top-4 -> gather -------
__global__ __launch_bounds__(256) void merge_rescore_gather_kernel(
    const float* __restrict__ query, const float* __restrict__ synth,
    const float* __restrict__ invn, const float* __restrict__ pScore,
    const int* __restrict__ pIdx, float* __restrict__ out) {
    const int row = blockIdx.x;
    const int t = threadIdx.x;
    const int l = t & 63;
    const int w = t >> 6;
    __shared__ float sS[256];
    __shared__ int sI[256];
    __shared__ int candIdx[NCAND];
    __shared__ float candScore[NCAND];
    __shared__ int topIdx[KNN];

    sS[t] = pScore[(size_t)row * 256 + t];
    sI[t] = pIdx[(size_t)row * 256 + t];
    __syncthreads();
    const float mv = sS[t];
    int cnt = 0;
    for (int j = 0; j < 256; ++j) {
        const float vj = sS[j];
        if (vj > mv || (vj == mv && j < t)) ++cnt;
    }
    if (cnt < NCAND) candIdx[cnt] = sI[t];
    __syncthreads();

    const float* qrow = query + ((size_t)row << 10);
#pragma unroll
    for (int u = 0; u < NCAND / 4; ++u) {
        const int cand = w * (NCAND / 4) + u;
        const int sidx = candIdx[cand];
        const float* srow = synth + ((size_t)sidx << 10);
        float ss = 0.f;
#pragma unroll
        for (int i = 0; i < 4; ++i) {
            const float4 a = *(const float4*)(qrow + l * 4 + i * 256);
            const float4 b = *(const float4*)(srow + l * 4 + i * 256);
            ss += a.x * b.x + a.y * b.y + a.z * b.z + a.w * b.w;
        }
#pragma unroll
        for (int off = 32; off > 0; off >>= 1) ss += __shfl_xor(ss, off, 64);
        if (l == 0) candScore[cand] = ss * invn[sidx];
    }
    __syncthreads();
    if (t == 0) {
        float bv0 = -1e30f, bv1 = -1e30f, bv2 = -1e30f, bv3 = -1e30f;
        int bi0 = 0, bi1 = 0, bi2 = 0, bi3 = 0;
        for (int c = 0; c < NCAND; ++c) {
            const float v = candScore[c];
            float mn = bv0; int mi = 0;
            if (bv1 < mn) { mn = bv1; mi = 1; }
            if (bv2 < mn) { mn = bv2; mi = 2; }
            if (bv3 < mn) { mn = bv3; mi = 3; }
            if (v > mn) {
                const int idx = candIdx[c];
                if (mi == 0)      { bv0 = v; bi0 = idx; }
                else if (mi == 1) { bv1 = v; bi1 = idx; }
                else if (mi == 2) { bv2 = v; bi2 = idx; }
                else              { bv3 = v; bi3 = idx; }
            }
        }
        topIdx[0] = bi0; topIdx[1] = bi1; topIdx[2] = bi2; topIdx[3] = bi3;
    }
    __syncthreads();
    const int d = t * 4;
    float4 s = make_float4(0.f, 0.f, 0.f, 0.f);
#pragma unroll
    for (int m = 0; m < KNN; ++m) {
        const float4 x = *(const float4*)(synth + ((size_t)topIdx[m] << 10) + d);
        s.x += x.x; s.y += x.y; s.z += x.z; s.w += x.w;
    }
    s.x *= 0.25f; s.y *= 0.25f; s.z *= 0.25f; s.w *= 0.25f;
    *(float4*)(out + ((size_t)(2 * row) << 10) + d) = s;
    *(float4*)(out + ((size_t)(2 * row + 1) << 10) + d) = s;
}

extern "C" void kernel_launch(void* const* d_in, const int* in_sizes, int n_in,
                              void* d_out, int out_size, void* d_ws, size_t ws_size,
                              hipStream_t stream) {
    const float* query = (const float*)d_in[0];   // (N1, DIM) fp32
    const float* synth = (const float*)d_in[1];   // (N2, DIM) fp32
    float* out = (float*)d_out;

    char* ws = (char*)d_ws;
    const size_t S8 = (size_t)N2 * DIM;           // 67108864
    const size_t Q8 = (size_t)N1 * DIM;           // 4194304
    const size_t INVN = (size_t)N2 * 4;           // 262144
    const size_t PART = (size_t)N1 * 256 * 4;     // 4194304
    uint8_t* sbf = (uint8_t*)ws;
    uint8_t* qbf = (uint8_t*)(ws + S8);
    float* invn = (float*)(ws + S8 + Q8);
    float* pScore = (float*)(ws + S8 + Q8 + INVN);
    int* pIdx = (int*)(ws + S8 + Q8 + INVN + PART);

    convert_fp8_kernel<<<N2 / 32, 256, 0, stream>>>(synth, sbf, invn);   // swizzled, x16/|s|
    convert_fp8_kernel<<<N1 / 32, 256, 0, stream>>>(query, qbf, nullptr); // swizzled
    dim3 g1(CSPLIT, N1 / BM);
    gemm_topk_fp8<<<g1, 256, 0, stream>>>(qbf, sbf, pScore, pIdx);
    merge_rescore_gather_kernel<<<N1, 256, 0, stream>>>(query, synth, invn,
                                                        pScore, pIdx, out);
}

// Round 8
// 954.921 us; speedup vs baseline: 1.4817x; 1.4817x over previous
//
#include <hip/hip_runtime.h>
#include <math.h>
#include <stdint.h>

#define N1 4096
#define N2 65536
#define DIM 1024
#define KNN 4
#define CSPLIT 32
#define BM 128
#define BN 128
#define COLS_PER_SPLIT (N2 / CSPLIT)          // 2048
#define TILES_PER_SPLIT (COLS_PER_SPLIT / BN) // 16
#define NCAND 32
#define SCSTR 68    // Sc stride (floats): 16B-aligned rows, bank-spread scans

typedef __attribute__((ext_vector_type(8))) int int32x8;
typedef __attribute__((ext_vector_type(4))) int int32x4;
typedef __attribute__((ext_vector_type(4))) float f32x4;

#define GLDS16(g, l)                                                          \
    __builtin_amdgcn_global_load_lds(                                         \
        (const __attribute__((address_space(1))) void*)(g),                   \
        (__attribute__((address_space(3))) void*)(l), 16, 0, 0)

// ---- fp32 -> fp8 e4m3fn (OCP), RNE, saturate to 448, subnormal-correct ----
__device__ __forceinline__ unsigned int f2fp8(float x) {
    const unsigned int u = __float_as_uint(x);
    const unsigned int s = (u >> 24) & 0x80u;
    const float ax = fminf(__uint_as_float(u & 0x7fffffffu), 448.f);
    int e = (int)(__float_as_uint(ax) >> 23) - 127;
    e = e < -6 ? -6 : e;
    const float q = rintf(ldexpf(ax, 3 - e));   // normals: [8,16]; subnorm: [0,8]
    return s | (unsigned int)((e + 6) * 8 + (int)q);  // q=16 carries into exponent
}

// ---------------- fp32 -> fp8 convert ----------------
// Row = 1024 fp8 bytes = 64 16B-units. Within each 128B K-slice (8 units), unit u
// stores source unit u ^ (row&7): 16B-unit XOR swizzle so the GEMM's ds_read_b128
// fragment reads are bank-uniform after forced-linear global_load_lds staging.
// Synth path (invn != nullptr): rows encoded as x*(16/|row|) -> GEMM scores are
// cosine*16 (uniform per-row scale, ranking unchanged; x16 keeps normalized
// elements out of the fp8 subnormal range). invn keeps TRUE 1/|row| for rescore.
__global__ void convert_fp8_kernel(const float* __restrict__ src,
                                   uint8_t* __restrict__ dst,
                                   float* __restrict__ invn) {
    const int t = threadIdx.x;
    const int row = blockIdx.x * 32 + (t >> 3);
    const int u = t & 7;
    const int sw = row & 7;                    // 16B-granularity swizzle
    const float* srow = src + ((size_t)row << 10);
    uint8_t* drow = dst + ((size_t)row << 10);
    float scale = 1.0f;
    if (invn != nullptr) {
        float ss = 0.f;
#pragma unroll
        for (int k = 0; k < 8; ++k) {
            const float* p = srow + ((k * 8 + (u ^ sw)) << 4);
#pragma unroll
            for (int g = 0; g < 4; ++g) {
                const float4 v = *(const float4*)(p + g * 4);
                ss += v.x * v.x + v.y * v.y + v.z * v.z + v.w * v.w;
            }
        }
#pragma unroll
        for (int off = 1; off < 8; off <<= 1) ss += __shfl_xor(ss, off, 64);
        const float inv = 1.0f / sqrtf(ss);
        scale = 16.0f * inv;
        if (u == 0) invn[row] = inv;
    }
#pragma unroll
    for (int k = 0; k < 8; ++k) {
        const float* p = srow + ((k * 8 + (u ^ sw)) << 4);
        unsigned int wv[4];
#pragma unroll
        for (int g = 0; g < 4; ++g) {
            const float4 v = *(const float4*)(p + g * 4);
            wv[g] = f2fp8(v.x * scale) | (f2fp8(v.y * scale) << 8) |
                    (f2fp8(v.z * scale) << 16) | (f2fp8(v.w * scale) << 24);
        }
        *(uint4*)(drow + ((k * 8 + u) << 4)) = make_uint4(wv[0], wv[1], wv[2], wv[3]);
    }
}

// ---------------- fp8 MFMA GEMM (K=128 scaled, scale==1.0) + running top-4 ----------------
// VERBATIM the verified 541us/21MB-write structure (R1): 2x32KB LDS dbuf, counted
// vmcnt(8) (vmcnt(0) only at st=7), stage body = barrier(A) -> frag reads ->
// lgkmcnt(0) -> barrier(B) -> DMA issue -> setprio(1) MFMA x16 setprio(0).
// Only change: invLds/invn machinery deleted (synth is prenormalized x16).
// Do NOT reorder this body: R3-R6 showed every perturbation (separate Sc, A-in-
// VGPR, unpinned region, sched_group_barrier) tips the allocator into a ~180MB
// scratch-spill round-trip at this tile shape.
__global__ __launch_bounds__(256, 2) void gemm_topk_fp8(
    const uint8_t* __restrict__ qbf, const uint8_t* __restrict__ sbf,
    float* __restrict__ pScore, int* __restrict__ pIdx) {
    __shared__ __align__(16) char smem[65536];   // [2][As 16K | Bs 16K]; Sc aliases
    float* const Sc = (float*)smem;

    const int tid = threadIdx.x;
    const int l = tid & 63;
    const int w = tid >> 6;
    const int waveM = w >> 1;
    const int waveN = w & 1;
    const int rowBase = blockIdx.y * BM;
    const int colSplit = blockIdx.x;
    const int colStart = colSplit * COLS_PER_SPLIT;

    // staging: wave w, instr i covers rows i*32 + w*8 + (l>>3), unit l&7
    const uint8_t* aSrc =
        qbf + ((size_t)(rowBase + w * 8 + (l >> 3)) << 10) + (l & 7) * 16;
    const uint8_t* bSrc0 =
        sbf + ((size_t)(colStart + w * 8 + (l >> 3)) << 10) + (l & 7) * 16;

    // fragment read: m = l&15, K-chunk q4 = l>>4. Source 16B units 2q4, 2q4+1 are
    // stored at positions (2q4)^(row&7), (2q4+1)^(row&7); row&7 == am&7.
    const int am = l & 15;
    const int q4 = l >> 4;
    const int u0 = (2 * q4) ^ (am & 7);
    const int u1 = u0 ^ 1;
    const int aOff = (waveM * 64 + am) * 128;   // + i*2048
    const int bOff = (waveN * 64 + am) * 128;   // + j*2048

    const unsigned int one_scales = 0x7f7f7f7fu;  // E8M0 127 -> x1.0 any byte

    const int scanRow = tid >> 1;
    const int scanSub = tid & 1;
    float tv0 = -1e30f, tv1 = -1e30f, tv2 = -1e30f, tv3 = -1e30f;
    int ti0 = colStart, ti1 = colStart, ti2 = colStart, ti3 = colStart;
    float thr = -1e30f;                          // == min(tv0..tv3), cached

    for (int tile = 0; tile < TILES_PER_SPLIT; ++tile) {
        const int colBase = colStart + tile * BN;
        const uint8_t* bSrc = bSrc0 + ((size_t)tile << 17);  // +tile*128*1024
        __syncthreads();                 // prev tile's Sc scan reads done

        auto stage_st = [&](int st) {    // 8 global_load_lds per wave per stage
            char* const dst = smem + (st & 1) * 32768 + w * 1024;
            const int kB = st << 7;
#pragma unroll
            for (int i = 0; i < 4; ++i) {
                GLDS16(aSrc + (size_t)i * 32768 + kB, dst + i * 4096);
                GLDS16(bSrc + (size_t)i * 32768 + kB, dst + 16384 + i * 4096);
            }
        };
        stage_st(0);                     // prologue: 16 loads in flight
        stage_st(1);

        f32x4 acc[4][4];
#pragma unroll
        for (int i = 0; i < 4; ++i)
#pragma unroll
            for (int j = 0; j < 4; ++j) acc[i][j] = (f32x4)0.f;

#pragma unroll
        for (int st = 0; st < 8; ++st) {
            // wait for stage st's 8 loads; stage st+1's 8 (the newest) stay in flight
            if (st < 7) asm volatile("s_waitcnt vmcnt(8)" ::: "memory");
            else        asm volatile("s_waitcnt vmcnt(0)" ::: "memory");
            __builtin_amdgcn_s_barrier();            // (A) all waves' st data visible
            __builtin_amdgcn_sched_barrier(0);
            const char* const curA = smem + (st & 1) * 32768;
            const char* const curB = curA + 16384;
            int32x8 af[4], bf[4];
#pragma unroll
            for (int i = 0; i < 4; ++i) {
                const int32x4 lo = *(const int32x4*)(curA + aOff + i * 2048 + u0 * 16);
                const int32x4 hi = *(const int32x4*)(curA + aOff + i * 2048 + u1 * 16);
                af[i] = __builtin_shufflevector(lo, hi, 0, 1, 2, 3, 4, 5, 6, 7);
            }
#pragma unroll
            for (int j = 0; j < 4; ++j) {
                const int32x4 lo = *(const int32x4*)(curB + bOff + j * 2048 + u0 * 16);
                const int32x4 hi = *(const int32x4*)(curB + bOff + j * 2048 + u1 * 16);
                bf[j] = __builtin_shufflevector(lo, hi, 0, 1, 2, 3, 4, 5, 6, 7);
            }
            asm volatile("s_waitcnt lgkmcnt(0)" ::: "memory");
            __builtin_amdgcn_sched_barrier(0);       // pin MFMA below the wait
            __builtin_amdgcn_s_barrier();            // (B) all reads of buf done
            if (st < 6) stage_st(st + 2);            // overwrite safe; stays in flight
            __builtin_amdgcn_s_setprio(1);
#pragma unroll
            for (int i = 0; i < 4; ++i)
#pragma unroll
                for (int j = 0; j < 4; ++j)
                    acc[i][j] = __builtin_amdgcn_mfma_scale_f32_16x16x128_f8f6f4(
                        af[i], bf[j], acc[i][j], 0, 0,   // cbsz=0 (e4m3), blgp=0
                        0, one_scales, 0, one_scales);   // opsel,scaleA, opsel,scaleB
            __builtin_amdgcn_s_setprio(0);
        }

        // epilogue: scores through Sc (aliases As/Bs - K-loop drained at st=7)
#pragma unroll
        for (int h = 0; h < 2; ++h) {
            if (waveN == h) {
#pragma unroll
                for (int i = 0; i < 4; ++i)
#pragma unroll
                    for (int j = 0; j < 4; ++j) {
                        const int scCol = j * 16 + am;
#pragma unroll
                        for (int r = 0; r < 4; ++r) {
                            const int scRow = waveM * 64 + i * 16 + q4 * 4 + r;
                            Sc[scRow * SCSTR + scCol] = acc[i][j][r];
                        }
                    }
            }
            __syncthreads();
            // threshold-gated vectorized scan: 2 threads/row, 32 cols each (8 x b128)
            const int sBase = scanRow * SCSTR + scanSub * 32;
#pragma unroll
            for (int c4 = 0; c4 < 8; ++c4) {
                const f32x4 v = *(const f32x4*)(Sc + sBase + c4 * 4);
                const float m4 = fmaxf(fmaxf(v[0], v[1]), fmaxf(v[2], v[3]));
                if (m4 > thr) {
#pragma unroll
                    for (int e = 0; e < 4; ++e) {
                        const float val = v[e];
                        if (val > thr) {
                            float mn = tv0; int mi = 0;
                            if (tv1 < mn) { mn = tv1; mi = 1; }
                            if (tv2 < mn) { mn = tv2; mi = 2; }
                            if (tv3 < mn) { mn = tv3; mi = 3; }
                            const int idx = colBase + h * 64 + scanSub * 32 + c4 * 4 + e;
                            if (mi == 0)      { tv0 = val; ti0 = idx; }
                            else if (mi == 1) { tv1 = val; ti1 = idx; }
                            else if (mi == 2) { tv2 = val; ti2 = idx; }
                            else              { tv3 = val; ti3 = idx; }
                            thr = fminf(fminf(tv0, tv1), fminf(tv2, tv3));
                        }
                    }
                }
            }
            if (h == 0) __syncthreads();  // scan reads done before h=1 Sc writes
        }
    }

    const int prow = rowBase + scanRow;
    const size_t pbase = (((size_t)prow * CSPLIT + colSplit) * 2 + scanSub) * 4;
    pScore[pbase + 0] = tv0; pIdx[pbase + 0] = ti0;
    pScore[pbase + 1] = tv1; pIdx[pbase + 1] = ti1;
    pScore[pbase + 2] = tv2; pIdx[pbase + 2] = ti2;
    pScore[pbase + 3] = tv3; pIdx[pbase + 3] = ti3;
}

// ------- merge 256 partials -> approx top-32 -> exact fp32 rescore -> top-4 -> gather -------
__global__ __launch_bounds__(256) void merge_rescore_gather_kernel(
    const float* __restrict__ query, const float* __restrict__ synth,
    const float* __restrict__ invn, const float* __restrict__ pScore,
    const int* __restrict__ pIdx, float* __restrict__ out) {
    const int row = blockIdx.x;
    const int t = threadIdx.x;
    const int l = t & 63;
    const int w = t >> 6;
    __shared__ float sS[256];
    __shared__ int sI[256];
    __shared__ int candIdx[NCAND];
    __shared__ float candScore[NCAND];
    __shared__ int topIdx[KNN];

    sS[t] = pScore[(size_t)row * 256 + t];
    sI[t] = pIdx[(size_t)row * 256 + t];
    __syncthreads();
    const float mv = sS[t];
    int cnt = 0;
    for (int j = 0; j < 256; ++j) {
        const float vj = sS[j];
        if (vj > mv || (vj == mv && j < t)) ++cnt;
    }
    if (cnt < NCAND) candIdx[cnt] = sI[t];
    __syncthreads();

    const float* qrow = query + ((size_t)row << 10);
#pragma unroll
    for (int u = 0; u < NCAND / 4; ++u) {
        const int cand = w * (NCAND / 4) + u;
        const int sidx = candIdx[cand];
        const float* srow = synth + ((size_t)sidx << 10);
        float ss = 0.f;
#pragma unroll
        for (int i = 0; i < 4; ++i) {
            const float4 a = *(const float4*)(qrow + l * 4 + i * 256);
            const float4 b = *(const float4*)(srow + l * 4 + i * 256);
            ss += a.x * b.x + a.y * b.y + a.z * b.z + a.w * b.w;
        }
#pragma unroll
        for (int off = 32; off > 0; off >>= 1) ss += __shfl_xor(ss, off, 64);
        if (l == 0) candScore[cand] = ss * invn[sidx];
    }
    __syncthreads();
    if (t == 0) {
        float bv0 = -1e30f, bv1 = -1e30f, bv2 = -1e30f, bv3 = -1e30f;
        int bi0 = 0, bi1 = 0, bi2 = 0, bi3 = 0;
        for (int c = 0; c < NCAND; ++c) {
            const float v = candScore[c];
            float mn = bv0; int mi = 0;
            if (bv1 < mn) { mn = bv1; mi = 1; }
            if (bv2 < mn) { mn = bv2; mi = 2; }
            if (bv3 < mn) { mn = bv3; mi = 3; }
            if (v > mn) {
                const int idx = candIdx[c];
                if (mi == 0)      { bv0 = v; bi0 = idx; }
                else if (mi == 1) { bv1 = v; bi1 = idx; }
                else if (mi == 2) { bv2 = v; bi2 = idx; }
                else              { bv3 = v; bi3 = idx; }
            }
        }
        topIdx[0] = bi0; topIdx[1] = bi1; topIdx[2] = bi2; topIdx[3] = bi3;
    }
    __syncthreads();
    const int d = t * 4;
    float4 s = make_float4(0.f, 0.f, 0.f, 0.f);
#pragma unroll
    for (int m = 0; m < KNN; ++m) {
        const float4 x = *(const float4*)(synth + ((size_t)topIdx[m] << 10) + d);
        s.x += x.x; s.y += x.y; s.z += x.z; s.w += x.w;
    }
    s.x *= 0.25f; s.y *= 0.25f; s.z *= 0.25f; s.w *= 0.25f;
    *(float4*)(out + ((size_t)(2 * row) << 10) + d) = s;
    *(float4*)(out + ((size_t)(2 * row + 1) << 10) + d) = s;
}

extern "C" void kernel_launch(void* const* d_in, const int* in_sizes, int n_in,
                              void* d_out, int out_size, void* d_ws, size_t ws_size,
                              hipStream_t stream) {
    const float* query = (const float*)d_in[0];   // (N1, DIM) fp32
    const float* synth = (const float*)d_in[1];   // (N2, DIM) fp32
    float* out = (float*)d_out;

    char* ws = (char*)d_ws;
    const size_t S8 = (size_t)N2 * DIM;           // 67108864
    const size_t Q8 = (size_t)N1 * DIM;           // 4194304
    const size_t INVN = (size_t)N2 * 4;           // 262144
    const size_t PART = (size_t)N1 * 256 * 4;     // 4194304
    uint8_t* sbf = (uint8_t*)ws;
    uint8_t* qbf = (uint8_t*)(ws + S8);
    float* invn = (float*)(ws + S8 + Q8);
    float* pScore = (float*)(ws + S8 + Q8 + INVN);
    int* pIdx = (int*)(ws + S8 + Q8 + INVN + PART);

    convert_fp8_kernel<<<N2 / 32, 256, 0, stream>>>(synth, sbf, invn);   // swizzled, x16/|s|
    convert_fp8_kernel<<<N1 / 32, 256, 0, stream>>>(query, qbf, nullptr); // swizzled
    dim3 g1(CSPLIT, N1 / BM);
    gemm_topk_fp8<<<g1, 256, 0, stream>>>(qbf, sbf, pScore, pIdx);
    merge_rescore_gather_kernel<<<N1, 256, 0, stream>>>(query, synth, invn,
                                                        pScore, pIdx, out);
}